// Round 1
// baseline (544.504 us; speedup 1.0000x reference)
//
#include <hip/hip_runtime.h>

#define D 128

// ---------------------------------------------------------------------------
// Degree counting: 1.6M int atomics, cheap.
// ---------------------------------------------------------------------------
__global__ void count_deg_kernel(const int* __restrict__ src, const int* __restrict__ dst,
                                 int* __restrict__ cnt_out, int* __restrict__ cnt_in, int nE) {
    int e = blockIdx.x * 256 + threadIdx.x;
    if (e < nE) {
        atomicAdd(&cnt_out[src[e]], 1);
        atomicAdd(&cnt_in[dst[e]], 1);
    }
}

// ---------------------------------------------------------------------------
// Exclusive prefix sum over in-degrees -> row_ptr (and pos copy for bucket
// fill). Single block, 1024 threads, wave-shuffle scan (wave=64).
// ---------------------------------------------------------------------------
__global__ __launch_bounds__(1024) void scan_kernel(const int* __restrict__ deg,
                                                    int* __restrict__ rp,
                                                    int* __restrict__ pos, int n) {
    __shared__ int wsum[16];
    __shared__ int carry_s;
    const int t = threadIdx.x;
    const int lane = t & 63;
    const int wid = t >> 6;
    if (t == 0) carry_s = 0;
    __syncthreads();
    for (int base = 0; base < n; base += 1024) {
        const int i = base + t;
        const int v = (i < n) ? deg[i] : 0;
        int s = v;
#pragma unroll
        for (int off = 1; off < 64; off <<= 1) {
            int u = __shfl_up(s, off, 64);
            if (lane >= off) s += u;
        }
        if (lane == 63) wsum[wid] = s;
        __syncthreads();
        if (wid == 0) {
            int ws = (lane < 16) ? wsum[lane] : 0;
#pragma unroll
            for (int off = 1; off < 16; off <<= 1) {
                int u = __shfl_up(ws, off, 64);
                if (lane >= off) ws += u;
            }
            if (lane < 16) wsum[lane] = ws;
        }
        __syncthreads();
        const int wprefix = (wid > 0) ? wsum[wid - 1] : 0;
        const int total = wsum[15];
        const int excl = s + wprefix - v + carry_s;
        if (i < n) { rp[i] = excl; pos[i] = excl; }
        __syncthreads();  // all reads of carry_s/wsum done
        if (t == 0) carry_s += total;
        __syncthreads();
    }
    if (t == 0) rp[n] = carry_s;
}

// ---------------------------------------------------------------------------
// Counting-sort bucket fill: srcs_sorted holds src ids grouped by dst.
// ---------------------------------------------------------------------------
__global__ void fill_csr_kernel(const int* __restrict__ src, const int* __restrict__ dst,
                                int* __restrict__ pos, int* __restrict__ srcs_sorted, int nE) {
    int e = blockIdx.x * 256 + threadIdx.x;
    if (e < nE) {
        int p = atomicAdd(&pos[dst[e]], 1);
        srcs_sorted[p] = src[e];
    }
}

// ---------------------------------------------------------------------------
// norms: rsqrt(max(deg,1))
// ---------------------------------------------------------------------------
__global__ void norms_kernel(const int* __restrict__ cnt_out, const int* __restrict__ cnt_in,
                             float* __restrict__ onorm, float* __restrict__ inorm, int n) {
    int i = blockIdx.x * 256 + threadIdx.x;
    if (i < n) {
        onorm[i] = rsqrtf(fmaxf((float)cnt_out[i], 1.0f));
        inorm[i] = rsqrtf(fmaxf((float)cnt_in[i], 1.0f));
    }
}

// ---------------------------------------------------------------------------
// Aggregation: agg[n,:] = sum_{e: dst==n} x[src_e,:] * onorm[src_e]
// 32 threads per node (float4 lanes), 8 nodes per 256-thread block.
// No atomics; coalesced 512B row reads that hit L2/L3.
// ---------------------------------------------------------------------------
__global__ __launch_bounds__(256) void aggregate_kernel(const float* __restrict__ x,
                                                        const float* __restrict__ onorm,
                                                        const int* __restrict__ rp,
                                                        const int* __restrict__ srcs,
                                                        float* __restrict__ agg, int n_nodes) {
    const int node = blockIdx.x * 8 + (threadIdx.x >> 5);
    const int lane = threadIdx.x & 31;
    if (node >= n_nodes) return;
    const int e0 = rp[node];
    const int e1 = rp[node + 1];
    float4 acc = make_float4(0.f, 0.f, 0.f, 0.f);
    for (int e = e0; e < e1; ++e) {
        const int s = srcs[e];
        const float nm = onorm[s];
        const float4 v = ((const float4*)(x + (size_t)s * D))[lane];
        acc.x = fmaf(v.x, nm, acc.x);
        acc.y = fmaf(v.y, nm, acc.y);
        acc.z = fmaf(v.z, nm, acc.z);
        acc.w = fmaf(v.w, nm, acc.w);
    }
    ((float4*)(agg + (size_t)node * D))[lane] = acc;
}

// ---------------------------------------------------------------------------
// GEMM + epilogue: out[n,c] = act((sum_k A[n,k]*W[k,c]) * inorm[n] + b[c])
// fp32 on vector ALU (no fp32 MFMA on CDNA4). W fully LDS-resident (64KB),
// A staged in 128-row chunks (66KB w/ pad). 512 threads; micro-tile 8 rows x
// 4 cols per thread -> 32 FMA per (8 scalar-broadcast + 1 b128) LDS reads.
// ---------------------------------------------------------------------------
template <bool RELU>
__global__ __launch_bounds__(512) void gemm_epi_kernel(const float* __restrict__ A,
                                                       const float* __restrict__ W,
                                                       const float* __restrict__ b,
                                                       const float* __restrict__ inorm,
                                                       float* __restrict__ out, int nrows) {
    __shared__ float sW[D * D];        // 64 KB
    __shared__ float sA[128 * 132];    // 66 KB, row stride 132 (16B-aligned rows)
    const int t = threadIdx.x;
    const int tc = t & 31;    // 32 col-groups of 4 -> 128 cols
    const int tr = t >> 5;    // 16 row-groups of 8 -> 128 rows

    // Load W once (4096 float4 / 512 threads = 8 each)
    for (int i = t; i < D * D / 4; i += 512)
        ((float4*)sW)[i] = ((const float4*)W)[i];

    const float4 bv = *(const float4*)&b[tc * 4];

    const int row0 = blockIdx.x * 128;
    const int rows = min(128, nrows - row0);

    // Stage A chunk: rows x 128 floats, as float4
    for (int i = t; i < rows * 32; i += 512) {
        const int r = i >> 5;
        const int k4 = i & 31;
        *(float4*)&sA[r * 132 + k4 * 4] = ((const float4*)(A + (size_t)(row0 + r) * D))[k4];
    }
    __syncthreads();

    float acc[8][4];
#pragma unroll
    for (int i = 0; i < 8; ++i)
#pragma unroll
        for (int j = 0; j < 4; ++j) acc[i][j] = 0.f;

#pragma unroll 4
    for (int k = 0; k < D; ++k) {
        const float4 wv = *(const float4*)&sW[k * D + tc * 4];
#pragma unroll
        for (int i = 0; i < 8; ++i) {
            const float a = sA[(tr * 8 + i) * 132 + k];
            acc[i][0] = fmaf(a, wv.x, acc[i][0]);
            acc[i][1] = fmaf(a, wv.y, acc[i][1]);
            acc[i][2] = fmaf(a, wv.z, acc[i][2]);
            acc[i][3] = fmaf(a, wv.w, acc[i][3]);
        }
    }

#pragma unroll
    for (int i = 0; i < 8; ++i) {
        const int r = tr * 8 + i;
        if (r < rows) {
            const float nm = inorm[row0 + r];
            float4 o;
            o.x = fmaf(acc[i][0], nm, bv.x);
            o.y = fmaf(acc[i][1], nm, bv.y);
            o.z = fmaf(acc[i][2], nm, bv.z);
            o.w = fmaf(acc[i][3], nm, bv.w);
            if (RELU) {
                o.x = fmaxf(o.x, 0.f); o.y = fmaxf(o.y, 0.f);
                o.z = fmaxf(o.z, 0.f); o.w = fmaxf(o.w, 0.f);
            }
            *(float4*)&out[(size_t)(row0 + r) * D + tc * 4] = o;
        }
    }
}

// ---------------------------------------------------------------------------
// Host launch
// ---------------------------------------------------------------------------
extern "C" void kernel_launch(void* const* d_in, const int* in_sizes, int n_in,
                              void* d_out, int out_size, void* d_ws, size_t ws_size,
                              hipStream_t stream) {
    const float* x   = (const float*)d_in[0];
    const int*   src = (const int*)d_in[1];
    const int*   dst = (const int*)d_in[2];
    const float* W1  = (const float*)d_in[3];
    const float* b1  = (const float*)d_in[4];
    const float* W2  = (const float*)d_in[5];
    const float* b2  = (const float*)d_in[6];
    const float* W3  = (const float*)d_in[7];
    const float* b3  = (const float*)d_in[8];

    const int N = in_sizes[0] / D;   // 50000
    const int E = in_sizes[1];       // 800000

    // Workspace carve (256B aligned)
    char* p = (char*)d_ws;
    auto alloc = [&](size_t bytes) -> void* {
        void* r = (void*)p;
        p += (bytes + 255) & ~(size_t)255;
        return r;
    };
    int*   cnt_out = (int*)alloc((size_t)N * 4);
    int*   cnt_in  = (int*)alloc((size_t)N * 4);
    int*   rp      = (int*)alloc((size_t)(N + 1) * 4);
    int*   pos     = (int*)alloc((size_t)N * 4);
    float* onorm   = (float*)alloc((size_t)N * 4);
    float* inorm   = (float*)alloc((size_t)N * 4);
    int*   srcs    = (int*)alloc((size_t)E * 4);
    float* bufA    = (float*)alloc((size_t)N * D * 4);
    float* bufB    = (float*)alloc((size_t)N * D * 4);
    float* outf    = (float*)d_out;

    // Graph build (once per call; ws is re-poisoned so counters must be zeroed)
    hipMemsetAsync(cnt_out, 0, (size_t)N * 4, stream);
    hipMemsetAsync(cnt_in, 0, (size_t)N * 4, stream);
    count_deg_kernel<<<(E + 255) / 256, 256, 0, stream>>>(src, dst, cnt_out, cnt_in, E);
    scan_kernel<<<1, 1024, 0, stream>>>(cnt_in, rp, pos, N);
    norms_kernel<<<(N + 255) / 256, 256, 0, stream>>>(cnt_out, cnt_in, onorm, inorm, N);
    fill_csr_kernel<<<(E + 255) / 256, 256, 0, stream>>>(src, dst, pos, srcs, E);

    const int aggGrid = (N + 7) / 8;
    const int gemmGrid = (N + 127) / 128;

    // Layer 1: agg(x) -> bufA; relu((bufA@W1)*inorm + b1) -> bufB
    aggregate_kernel<<<aggGrid, 256, 0, stream>>>(x, onorm, rp, srcs, bufA, N);
    gemm_epi_kernel<true><<<gemmGrid, 512, 0, stream>>>(bufA, W1, b1, inorm, bufB, N);
    // Layer 2
    aggregate_kernel<<<aggGrid, 256, 0, stream>>>(bufB, onorm, rp, srcs, bufA, N);
    gemm_epi_kernel<true><<<gemmGrid, 512, 0, stream>>>(bufA, W2, b2, inorm, bufB, N);
    // Layer 3 (no relu), straight to d_out
    aggregate_kernel<<<aggGrid, 256, 0, stream>>>(bufB, onorm, rp, srcs, bufA, N);
    gemm_epi_kernel<false><<<gemmGrid, 512, 0, stream>>>(bufA, W3, b3, inorm, outf, N);
}

// Round 2
// 490.566 us; speedup vs baseline: 1.1100x; 1.1100x over previous
//
#include <hip/hip_runtime.h>

#define D 128

// ---------------------------------------------------------------------------
// Degree counting + rank capture. The in-degree atomic's return value is the
// edge's slot within its dst bucket -> fill_csr needs no atomics.
// Device-scope atomics execute memory-side on gfx950 (49.8MB WRITE_SIZE for
// 200KB of counters, R1 rocprof) — unavoidable here, but paid only once.
// ---------------------------------------------------------------------------
__global__ void count_deg_kernel(const int* __restrict__ src, const int* __restrict__ dst,
                                 int* __restrict__ cnt_out, int* __restrict__ cnt_in,
                                 int* __restrict__ rank, int nE) {
    int e = blockIdx.x * 256 + threadIdx.x;
    if (e < nE) {
        atomicAdd(&cnt_out[src[e]], 1);
        rank[e] = atomicAdd(&cnt_in[dst[e]], 1);
    }
}

// ---------------------------------------------------------------------------
// Multi-block exclusive scan, stage 1: per-block (1024 elems) scan + block sum.
// ---------------------------------------------------------------------------
__global__ __launch_bounds__(1024) void scan_block_kernel(const int* __restrict__ deg,
                                                          int* __restrict__ rp,
                                                          int* __restrict__ bsum, int n) {
    __shared__ int wsum[16];
    const int t = threadIdx.x;
    const int lane = t & 63;
    const int wid = t >> 6;
    const int i = blockIdx.x * 1024 + t;
    const int v = (i < n) ? deg[i] : 0;
    int s = v;
#pragma unroll
    for (int off = 1; off < 64; off <<= 1) {
        int u = __shfl_up(s, off, 64);
        if (lane >= off) s += u;
    }
    if (lane == 63) wsum[wid] = s;
    __syncthreads();
    if (wid == 0) {
        int ws = (lane < 16) ? wsum[lane] : 0;
#pragma unroll
        for (int off = 1; off < 16; off <<= 1) {
            int u = __shfl_up(ws, off, 64);
            if (lane >= off) ws += u;
        }
        if (lane < 16) wsum[lane] = ws;
    }
    __syncthreads();
    const int excl = s - v + ((wid > 0) ? wsum[wid - 1] : 0);
    if (i < n) rp[i] = excl;
    if (t == 0) bsum[blockIdx.x] = wsum[15];
}

// ---------------------------------------------------------------------------
// Stage 2: one wave scans the block sums (exclusive, in place), writes total.
// Handles nb up to any size via 64-wide chunks with carry (nb=49 here).
// ---------------------------------------------------------------------------
__global__ void scan_partials_kernel(int* __restrict__ bsum, int* __restrict__ rp_total, int nb) {
    const int lane = threadIdx.x;  // 64 threads
    int carry = 0;
    for (int base = 0; base < nb; base += 64) {
        const int i = base + lane;
        const int v = (i < nb) ? bsum[i] : 0;
        int s = v;
#pragma unroll
        for (int off = 1; off < 64; off <<= 1) {
            int u = __shfl_up(s, off, 64);
            if (lane >= off) s += u;
        }
        if (i < nb) bsum[i] = s - v + carry;
        carry += __shfl(s, 63, 64);
    }
    if (lane == 0) rp_total[0] = carry;
}

// ---------------------------------------------------------------------------
// Stage 3 (fused with norms): add block offsets, compute rsqrt norms.
// ---------------------------------------------------------------------------
__global__ __launch_bounds__(1024) void finalize_kernel(int* __restrict__ rp,
                                                        const int* __restrict__ bsum,
                                                        const int* __restrict__ cnt_out,
                                                        const int* __restrict__ cnt_in,
                                                        float* __restrict__ onorm,
                                                        float* __restrict__ inorm, int n) {
    const int i = blockIdx.x * 1024 + threadIdx.x;
    if (i < n) {
        rp[i] += bsum[blockIdx.x];
        onorm[i] = rsqrtf(fmaxf((float)cnt_out[i], 1.0f));
        inorm[i] = rsqrtf(fmaxf((float)cnt_in[i], 1.0f));
    }
}

// ---------------------------------------------------------------------------
// Atomic-free CSR fill using captured ranks.
// ---------------------------------------------------------------------------
__global__ void fill_csr_kernel(const int* __restrict__ src, const int* __restrict__ dst,
                                const int* __restrict__ rank, const int* __restrict__ rp,
                                int* __restrict__ srcs_sorted, int nE) {
    int e = blockIdx.x * 256 + threadIdx.x;
    if (e < nE) {
        srcs_sorted[rp[dst[e]] + rank[e]] = src[e];
    }
}

// ---------------------------------------------------------------------------
// Aggregation: agg[n,:] = sum_{e: dst==n} x[src_e,:] (* onorm[src_e] if SCALE)
// Layers 2/3 read features pre-scaled by the previous GEMM epilogue, so their
// inner loop is a pure gather-add (no dependent onorm load). Unroll-by-2 with
// dual accumulators for memory-level parallelism.
// ---------------------------------------------------------------------------
template <bool SCALE>
__global__ __launch_bounds__(256) void aggregate_kernel(const float* __restrict__ x,
                                                        const float* __restrict__ onorm,
                                                        const int* __restrict__ rp,
                                                        const int* __restrict__ srcs,
                                                        float* __restrict__ agg, int n_nodes) {
    const int node = blockIdx.x * 8 + (threadIdx.x >> 5);
    const int lane = threadIdx.x & 31;
    if (node >= n_nodes) return;
    const int e0 = rp[node];
    const int e1 = rp[node + 1];
    const float4* __restrict__ x4 = (const float4*)x;
    float4 a0 = make_float4(0.f, 0.f, 0.f, 0.f);
    float4 a1 = make_float4(0.f, 0.f, 0.f, 0.f);
    int e = e0;
    for (; e + 2 <= e1; e += 2) {
        const int s0 = srcs[e];
        const int s1 = srcs[e + 1];
        const float4 v0 = x4[(size_t)s0 * 32 + lane];
        const float4 v1 = x4[(size_t)s1 * 32 + lane];
        if (SCALE) {
            const float n0 = onorm[s0];
            const float n1 = onorm[s1];
            a0.x = fmaf(v0.x, n0, a0.x); a0.y = fmaf(v0.y, n0, a0.y);
            a0.z = fmaf(v0.z, n0, a0.z); a0.w = fmaf(v0.w, n0, a0.w);
            a1.x = fmaf(v1.x, n1, a1.x); a1.y = fmaf(v1.y, n1, a1.y);
            a1.z = fmaf(v1.z, n1, a1.z); a1.w = fmaf(v1.w, n1, a1.w);
        } else {
            a0.x += v0.x; a0.y += v0.y; a0.z += v0.z; a0.w += v0.w;
            a1.x += v1.x; a1.y += v1.y; a1.z += v1.z; a1.w += v1.w;
        }
    }
    if (e < e1) {
        const int s0 = srcs[e];
        const float4 v0 = x4[(size_t)s0 * 32 + lane];
        if (SCALE) {
            const float n0 = onorm[s0];
            a0.x = fmaf(v0.x, n0, a0.x); a0.y = fmaf(v0.y, n0, a0.y);
            a0.z = fmaf(v0.z, n0, a0.z); a0.w = fmaf(v0.w, n0, a0.w);
        } else {
            a0.x += v0.x; a0.y += v0.y; a0.z += v0.z; a0.w += v0.w;
        }
    }
    a0.x += a1.x; a0.y += a1.y; a0.z += a1.z; a0.w += a1.w;
    ((float4*)(agg + (size_t)node * D))[lane] = a0;
}

// ---------------------------------------------------------------------------
// GEMM + epilogue: out[n,c] = post((sum_k A[n,k]*W[k,c]) * inorm[n] + b[c])
// post = relu (RELU) then * onorm[n] (OSCALE, feeds next layer's aggregate).
// fp32 vector-ALU GEMM (no fp32 MFMA on CDNA4). 256 threads, 128x128 tile,
// 8x8 micro-tile, k-step 4 with float4 LDS reads: per k4-iter 16 ds_read_b128
// vs 256 v_fma -> VALU-bound. LDS 130KB -> 1 block/CU, 4 waves saturate the
// 4 SIMDs on FMA throughput.
// ---------------------------------------------------------------------------
template <bool RELU, bool OSCALE>
__global__ __launch_bounds__(256) void gemm_epi_kernel(const float* __restrict__ A,
                                                       const float* __restrict__ W,
                                                       const float* __restrict__ b,
                                                       const float* __restrict__ inorm,
                                                       const float* __restrict__ onorm,
                                                       float* __restrict__ out, int nrows) {
    __shared__ float sW[D * D];        // 64 KB
    __shared__ float sA[128 * 132];    // 66 KB (stride 132 keeps 16B alignment)
    const int t = threadIdx.x;
    const int tc = t & 15;    // 16 col-groups of 8 cols
    const int tr = t >> 4;    // 16 row-groups of 8 rows

    for (int i = t; i < D * D / 4; i += 256)
        ((float4*)sW)[i] = ((const float4*)W)[i];

    const int row0 = blockIdx.x * 128;
    const int rows = min(128, nrows - row0);

    for (int i = t; i < rows * 32; i += 256) {
        const int r = i >> 5;
        const int k4 = i & 31;
        *(float4*)&sA[r * 132 + k4 * 4] = ((const float4*)(A + (size_t)(row0 + r) * D))[k4];
    }
    __syncthreads();

    float acc[8][8];
#pragma unroll
    for (int i = 0; i < 8; ++i)
#pragma unroll
        for (int j = 0; j < 8; ++j) acc[i][j] = 0.f;

    for (int k4 = 0; k4 < 32; ++k4) {
        float4 a4[8];
#pragma unroll
        for (int i = 0; i < 8; ++i)
            a4[i] = *(const float4*)&sA[(tr * 8 + i) * 132 + k4 * 4];
#pragma unroll
        for (int kk = 0; kk < 4; ++kk) {
            const float4 wlo = *(const float4*)&sW[(k4 * 4 + kk) * D + tc * 8];
            const float4 whi = *(const float4*)&sW[(k4 * 4 + kk) * D + tc * 8 + 4];
#pragma unroll
            for (int i = 0; i < 8; ++i) {
                const float av = ((const float*)&a4[i])[kk];
                acc[i][0] = fmaf(av, wlo.x, acc[i][0]);
                acc[i][1] = fmaf(av, wlo.y, acc[i][1]);
                acc[i][2] = fmaf(av, wlo.z, acc[i][2]);
                acc[i][3] = fmaf(av, wlo.w, acc[i][3]);
                acc[i][4] = fmaf(av, whi.x, acc[i][4]);
                acc[i][5] = fmaf(av, whi.y, acc[i][5]);
                acc[i][6] = fmaf(av, whi.z, acc[i][6]);
                acc[i][7] = fmaf(av, whi.w, acc[i][7]);
            }
        }
    }

    const float4 bv0 = *(const float4*)&b[tc * 8];
    const float4 bv1 = *(const float4*)&b[tc * 8 + 4];
#pragma unroll
    for (int i = 0; i < 8; ++i) {
        const int r = tr * 8 + i;
        if (r < rows) {
            const float nm = inorm[row0 + r];
            const float os = OSCALE ? onorm[row0 + r] : 1.0f;
            float4 o0, o1;
            o0.x = fmaf(acc[i][0], nm, bv0.x); o0.y = fmaf(acc[i][1], nm, bv0.y);
            o0.z = fmaf(acc[i][2], nm, bv0.z); o0.w = fmaf(acc[i][3], nm, bv0.w);
            o1.x = fmaf(acc[i][4], nm, bv1.x); o1.y = fmaf(acc[i][5], nm, bv1.y);
            o1.z = fmaf(acc[i][6], nm, bv1.z); o1.w = fmaf(acc[i][7], nm, bv1.w);
            if (RELU) {
                o0.x = fmaxf(o0.x, 0.f); o0.y = fmaxf(o0.y, 0.f);
                o0.z = fmaxf(o0.z, 0.f); o0.w = fmaxf(o0.w, 0.f);
                o1.x = fmaxf(o1.x, 0.f); o1.y = fmaxf(o1.y, 0.f);
                o1.z = fmaxf(o1.z, 0.f); o1.w = fmaxf(o1.w, 0.f);
            }
            if (OSCALE) {
                o0.x *= os; o0.y *= os; o0.z *= os; o0.w *= os;
                o1.x *= os; o1.y *= os; o1.z *= os; o1.w *= os;
            }
            float* op = &out[(size_t)(row0 + r) * D + tc * 8];
            *(float4*)op = o0;
            *(float4*)(op + 4) = o1;
        }
    }
}

// ---------------------------------------------------------------------------
// Host launch
// ---------------------------------------------------------------------------
extern "C" void kernel_launch(void* const* d_in, const int* in_sizes, int n_in,
                              void* d_out, int out_size, void* d_ws, size_t ws_size,
                              hipStream_t stream) {
    const float* x   = (const float*)d_in[0];
    const int*   src = (const int*)d_in[1];
    const int*   dst = (const int*)d_in[2];
    const float* W1  = (const float*)d_in[3];
    const float* b1  = (const float*)d_in[4];
    const float* W2  = (const float*)d_in[5];
    const float* b2  = (const float*)d_in[6];
    const float* W3  = (const float*)d_in[7];
    const float* b3  = (const float*)d_in[8];

    const int N = in_sizes[0] / D;   // 50000
    const int E = in_sizes[1];       // 800000

    char* p = (char*)d_ws;
    auto alloc = [&](size_t bytes) -> void* {
        void* r = (void*)p;
        p += (bytes + 255) & ~(size_t)255;
        return r;
    };
    int*   cnt_out = (int*)alloc((size_t)N * 4);
    int*   cnt_in  = (int*)alloc((size_t)N * 4);
    int*   rp      = (int*)alloc((size_t)(N + 1) * 4);
    int*   rank    = (int*)alloc((size_t)E * 4);
    int*   bsum    = (int*)alloc(1024 * 4);
    float* onorm   = (float*)alloc((size_t)N * 4);
    float* inorm   = (float*)alloc((size_t)N * 4);
    int*   srcs    = (int*)alloc((size_t)E * 4);
    float* bufA    = (float*)alloc((size_t)N * D * 4);
    float* bufB    = (float*)alloc((size_t)N * D * 4);
    float* outf    = (float*)d_out;

    // One memset spanning cnt_out..cnt_in (adjacent carve)
    hipMemsetAsync(cnt_out, 0, (size_t)((char*)cnt_in - (char*)cnt_out) + (size_t)N * 4, stream);

    const int nb = (N + 1023) / 1024;  // 49 scan blocks
    count_deg_kernel<<<(E + 255) / 256, 256, 0, stream>>>(src, dst, cnt_out, cnt_in, rank, E);
    scan_block_kernel<<<nb, 1024, 0, stream>>>(cnt_in, rp, bsum, N);
    scan_partials_kernel<<<1, 64, 0, stream>>>(bsum, &rp[N], nb);
    finalize_kernel<<<nb, 1024, 0, stream>>>(rp, bsum, cnt_out, cnt_in, onorm, inorm, N);
    fill_csr_kernel<<<(E + 255) / 256, 256, 0, stream>>>(src, dst, rank, rp, srcs, E);

    const int aggGrid = (N + 7) / 8;
    const int gemmGrid = (N + 127) / 128;

    // Layer 1: per-edge onorm scaling (x is unscaled input)
    aggregate_kernel<true><<<aggGrid, 256, 0, stream>>>(x, onorm, rp, srcs, bufA, N);
    gemm_epi_kernel<true, true><<<gemmGrid, 256, 0, stream>>>(bufA, W1, b1, inorm, onorm, bufB, N);
    // Layer 2: bufB already carries onorm scaling from epilogue
    aggregate_kernel<false><<<aggGrid, 256, 0, stream>>>(bufB, onorm, rp, srcs, bufA, N);
    gemm_epi_kernel<true, true><<<gemmGrid, 256, 0, stream>>>(bufA, W2, b2, inorm, onorm, bufB, N);
    // Layer 3: plain epilogue straight to d_out
    aggregate_kernel<false><<<aggGrid, 256, 0, stream>>>(bufB, onorm, rp, srcs, bufA, N);
    gemm_epi_kernel<false, false><<<gemmGrid, 256, 0, stream>>>(bufA, W3, b3, inorm, onorm, outf, N);
}